// Round 8
// baseline (288.884 us; speedup 1.0000x reference)
//
#include <hip/hip_runtime.h>

// ---------- common types ----------
typedef float  f32x4  __attribute__((ext_vector_type(4)));
typedef short  bf16x8 __attribute__((ext_vector_type(8)));

#define MFMA16(a, b, c) __builtin_amdgcn_mfma_f32_16x16x32_bf16((a), (b), (c), 0, 0, 0)

// global -> LDS direct DMA, 16B per lane. LDS dest is wave-uniform base +
// lane*16 (linear); global src is per-lane.
#define GLL16(g, l) __builtin_amdgcn_global_load_lds(                      \
    (const __attribute__((address_space(1))) void*)(g),                    \
    (__attribute__((address_space(3))) void*)(l), 16, 0, 0)

__device__ __forceinline__ short f2bf(float f) {
    union { float f; unsigned u; } a; a.f = f;
    unsigned r = a.u + 0x7fffu + ((a.u >> 16) & 1u);  // RNE
    return (short)(r >> 16);
}
__device__ __forceinline__ float bf2f(unsigned short u) {
    union { unsigned u; float f; } a; a.u = ((unsigned)u) << 16; return a.f;
}

// sizes
#define Bb   8
#define Nn   1024
#define DIM  768
#define HH   12
#define HD   64
#define INNER 768
#define SCALE 0.125f
// SCALE * log2(e): exp(s*SCALE) == exp2(s*SCL2E)
#define SCL2E 0.18033688011112042f

// ---------- prep kernels ----------
__global__ void cast_to_bf16(const float* __restrict__ in, short* __restrict__ out, int n4) {
    int i = blockIdx.x * 256 + threadIdx.x;
    if (i >= n4) return;
    float4 f = reinterpret_cast<const float4*>(in)[i];
    unsigned lo = (unsigned)(unsigned short)f2bf(f.x) | ((unsigned)(unsigned short)f2bf(f.y) << 16);
    unsigned hi = (unsigned)(unsigned short)f2bf(f.z) | ((unsigned)(unsigned short)f2bf(f.w) << 16);
    reinterpret_cast<uint2*>(out)[i] = make_uint2(lo, hi);
}

// wt[c][k] = w[k][c]; w is [rows=K][cols], wt is [cols][K]
__global__ void transpose_cast(const float* __restrict__ w, short* __restrict__ wt,
                               int rows, int cols) {
    int idx = blockIdx.x * 256 + threadIdx.x;
    if (idx >= rows * cols) return;
    int c = idx / rows;
    int k = idx - c * rows;
    wt[idx] = f2bf(w[k * cols + c]);
}

// ---------- GEMM v5 (R6, proven 57.4us): 3-buf counted-vmcnt + XCD swizzle ----------
// C[M,N] = A[M,K] @ Bt[N,K]^T. 128x128 tile, BK=32, 4 waves (2x2, 64x64 each).
// 3 LDS buffers, stage distance 2, counted vmcnt(4), raw s_barrier,
// lgkmcnt(0)+sched_barrier before MFMA, setprio around MFMA.
// XCD decode: y=(bid&7)*8+((bid>>3)&7), x=bid>>6 -> 8 co-resident blocks
// per XCD share one B-panel + an 8-row A-band (~1.8MB L2 working set).
// R7 lesson: 256x128 tile with 72KB LDS regressed (69us, occ still 20%);
// this 128^2 version is the best measured GEMM structure for this shape.
#define STAGE(ksv, bv)                                                      \
  { const int kc_ = (ksv) << 5;                                             \
    GLL16(A  + aoff + kc_,                  &As[bv][lch]);                  \
    GLL16(A  + aoff + (size_t)64 * K + kc_, &As[bv][2048 + lch]);           \
    GLL16(Bt + boff + kc_,                  &Bs[bv][lch]);                  \
    GLL16(Bt + boff + (size_t)64 * K + kc_, &Bs[bv][2048 + lch]); }

#define PHASE(VM, DO_STAGE)                                                 \
  {                                                                         \
    bf16x8 af[4], bfr[4];                                                   \
    _Pragma("unroll") for (int t = 0; t < 4; t++)                           \
      af[t] = *reinterpret_cast<const bf16x8*>(                             \
          &As[bi][(wrow * 64 + t * 16 + l16) * 32 + swo]);                  \
    _Pragma("unroll") for (int t = 0; t < 4; t++)                           \
      bfr[t] = *reinterpret_cast<const bf16x8*>(                            \
          &Bs[bi][(wcol * 64 + t * 16 + l16) * 32 + swo]);                  \
    if (DO_STAGE) { STAGE(ks + 2, bn); }                                    \
    asm volatile("s_waitcnt vmcnt(" #VM ")" ::: "memory");                  \
    __builtin_amdgcn_s_barrier();                                           \
    asm volatile("s_waitcnt lgkmcnt(0)" ::: "memory");                      \
    __builtin_amdgcn_sched_barrier(0);                                      \
    __builtin_amdgcn_s_setprio(1);                                          \
    _Pragma("unroll") for (int rt = 0; rt < 4; rt++)                        \
      _Pragma("unroll") for (int ct = 0; ct < 4; ct++)                      \
        acc[rt][ct] = MFMA16(af[rt], bfr[ct], acc[rt][ct]);                 \
    __builtin_amdgcn_s_setprio(0);                                          \
    __builtin_amdgcn_s_barrier();                                           \
  }

template <int MODE>
__global__ __launch_bounds__(256, 3)
void gemm128(const short* __restrict__ A, const short* __restrict__ Bt, int K,
             short* __restrict__ qb, short* __restrict__ kb, short* __restrict__ vtb,
             float* __restrict__ outp, const float* __restrict__ bias) {
    __shared__ __align__(16) short As[3][128 * 32];
    __shared__ __align__(16) short Bs[3][128 * 32];

    const int tid  = threadIdx.x;
    const int lane = tid & 63, wv = tid >> 6;
    const int wrow = wv >> 1, wcol = wv & 1;
    const int quad = lane >> 4, l16 = lane & 15;

    const int bid = blockIdx.x;
    const int m0 = (((bid & 7) << 3) | ((bid >> 3) & 7)) << 7;
    const int n0 = (bid >> 6) << 7;

    // ---- stage addressing ----
    // per GLL call: 4 waves x 64 lanes x 16B = 64 rows x 64B.
    // wave wv covers rows wv*16 + (lane>>2); LDS unit = lane&3 (linear),
    // global unit fetched = (lane&3) ^ ((row>>1)&3) = (lane&3)^((lane>>3)&3).
    const int row64 = (wv << 4) + (lane >> 2);
    const int gu = (lane & 3) ^ ((lane >> 3) & 3);
    const size_t aoff = (size_t)(m0 + row64) * K + gu * 8;
    const size_t boff = (size_t)(n0 + row64) * K + gu * 8;
    const int lch = wv * 512;

    f32x4 acc[4][4];
#pragma unroll
    for (int i = 0; i < 4; i++)
#pragma unroll
        for (int j = 0; j < 4; j++) acc[i][j] = (f32x4){0.f, 0.f, 0.f, 0.f};

    // read-side unswizzle: (row>>1)&3 == (l16>>1)&3 (t*16, wrow*64 are ≡0 mod 4)
    const int swo = (quad ^ ((l16 >> 1) & 3)) * 8;

    const int NK = K >> 5;  // 24

    STAGE(0, 0);
    STAGE(1, 1);
    asm volatile("s_waitcnt vmcnt(4)" ::: "memory");
    __builtin_amdgcn_s_barrier();

    int bi = 0, bn = 2;
    int ks = 0;
    for (; ks < NK - 2; ks++) {
        PHASE(4, true);
        bi = (bi == 2) ? 0 : bi + 1;
        bn = (bn == 2) ? 0 : bn + 1;
    }
    PHASE(0, false);
    bi = (bi == 2) ? 0 : bi + 1;
    PHASE(0, false);

    // epilogue: C/D layout col=lane&15, row=quad*4+reg
#pragma unroll
    for (int rt = 0; rt < 4; rt++) {
#pragma unroll
        for (int ct = 0; ct < 4; ct++) {
            const int c = n0 + wcol * 64 + ct * 16 + l16;
#pragma unroll
            for (int reg = 0; reg < 4; reg++) {
                const int r = m0 + wrow * 64 + rt * 16 + quad * 4 + reg;
                const float v = acc[rt][ct][reg];
                if (MODE == 0) {
                    const int b = r >> 10, n = r & 1023;
                    const int which = (c >= 1536) ? 2 : (c >= 768 ? 1 : 0);
                    const int cc = c - which * 768;
                    const int h = cc >> 6, d = cc & 63;
                    const int bh = b * HH + h;
                    const short bv = f2bf(v);
                    if (which == 0)      qb[(bh << 16) + (n << 6) + d] = bv;
                    else if (which == 1) kb[(bh << 16) + (n << 6) + d] = bv;
                    else                 vtb[(bh << 16) + (d << 10) + n] = bv;
                } else {
                    outp[(size_t)r * 768 + c] = v + bias[c];
                }
            }
        }
    }
}

// ---------- attention pass 1 v5: gll + double-buffer + XOR swizzle ----------
__global__ __launch_bounds__(512, 4)
void attn_den5(const short* __restrict__ qb, const short* __restrict__ kb,
               short* __restrict__ invp) {
    __shared__ __align__(16) short Qs[2][128 * 64];
    __shared__ __align__(16) short Ks[2][128 * 64];

    const int tid = threadIdx.x, lane = tid & 63, wv = tid >> 6;  // wv 0..7
    const int wrow = wv >> 2, wcol = wv & 3;                      // 2 x 4
    const int quad = lane >> 4, l16 = lane & 15;
    const int bid = blockIdx.x;
    const int b = bid & 7;
    const int nmt = bid >> 3;            // 0..63
    const int n0 = (nmt >> 3) << 7;      // n128 base
    const int m0 = (nmt & 7) << 7;       // m128 base

    const int r8 = lane >> 3;                 // 0..7, == row&7
    const int gu = (lane & 7) ^ r8;           // pre-swizzled global unit
    const int qo0 = (n0 + wv * 8 + r8) * 64 + gu * 8;   // shorts
    const int qo1 = qo0 + 64 * 64;                      // +64 rows
    const int ko0 = (m0 + wv * 8 + r8) * 64 + gu * 8;
    const int ko1 = ko0 + 64 * 64;
    const int lc0 = wv * 512;                 // wave LDS chunk, it=0 (shorts)
    const int lc1 = 4096 + wv * 512;          // it=1

    f32x4 den[4][2];
#pragma unroll
    for (int i = 0; i < 4; i++)
#pragma unroll
        for (int j = 0; j < 2; j++) den[i][j] = (f32x4){0.f, 0.f, 0.f, 0.f};
    const f32x4 z = (f32x4){0.f, 0.f, 0.f, 0.f};

    {
        const short* qh = qb + ((size_t)(b * HH) << 16);
        const short* kh = kb + ((size_t)(b * HH) << 16);
        GLL16(qh + qo0, &Qs[0][lc0]);
        GLL16(qh + qo1, &Qs[0][lc1]);
        GLL16(kh + ko0, &Ks[0][lc0]);
        GLL16(kh + ko1, &Ks[0][lc1]);
    }

    for (int h = 0; h < HH; h++) {
        asm volatile("s_waitcnt vmcnt(0)" ::: "memory");  // this head's DMA landed
        __syncthreads();                                  // all waves see it
        if (h < HH - 1) {
            const int pn = (h + 1) & 1;
            const short* qh = qb + ((size_t)(b * HH + h + 1) << 16);
            const short* kh = kb + ((size_t)(b * HH + h + 1) << 16);
            GLL16(qh + qo0, &Qs[pn][lc0]);
            GLL16(qh + qo1, &Qs[pn][lc1]);
            GLL16(kh + ko0, &Ks[pn][lc0]);
            GLL16(kh + ko1, &Ks[pn][lc1]);
        }
        const int pb = h & 1;
        const int sw0 = (quad ^ (l16 & 7)) * 8;

        bf16x8 aq[4][2], bk[2][2];
#pragma unroll
        for (int t = 0; t < 4; t++) {
            const int row = wrow * 64 + t * 16 + l16;
            aq[t][0] = *reinterpret_cast<bf16x8*>(&Qs[pb][row * 64 + sw0]);
            aq[t][1] = *reinterpret_cast<bf16x8*>(&Qs[pb][row * 64 + (sw0 ^ 32)]);
        }
#pragma unroll
        for (int t = 0; t < 2; t++) {
            const int row = wcol * 32 + t * 16 + l16;
            bk[t][0] = *reinterpret_cast<bf16x8*>(&Ks[pb][row * 64 + sw0]);
            bk[t][1] = *reinterpret_cast<bf16x8*>(&Ks[pb][row * 64 + (sw0 ^ 32)]);
        }
#pragma unroll
        for (int nt = 0; nt < 4; nt++)
#pragma unroll
            for (int mt = 0; mt < 2; mt++) {
                f32x4 s = MFMA16(aq[nt][0], bk[mt][0], z);
                s = MFMA16(aq[nt][1], bk[mt][1], s);
#pragma unroll
                for (int r = 0; r < 4; r++)
                    den[nt][mt][r] += __builtin_amdgcn_exp2f(s[r] * SCL2E);
            }
    }

#pragma unroll
    for (int nt = 0; nt < 4; nt++)
#pragma unroll
        for (int mt = 0; mt < 2; mt++) {
            const int ntg = (n0 >> 4) + wrow * 4 + nt;
            const int mtg = (m0 >> 4) + wcol * 2 + mt;
            ushort4 o;
            o.x = (unsigned short)f2bf(1.0f / den[nt][mt][0]);
            o.y = (unsigned short)f2bf(1.0f / den[nt][mt][1]);
            o.z = (unsigned short)f2bf(1.0f / den[nt][mt][2]);
            o.w = (unsigned short)f2bf(1.0f / den[nt][mt][3]);
            *reinterpret_cast<ushort4*>(&invp[(((b * 64 + ntg) * 64 + mtg) * 64 + lane) * 4]) = o;
        }
}

// ---------- attention pass 2 v3: no-K/V-LDS, zero-barrier ----------
// Block = (b, h, n128): 768 blocks (3/CU), 4 waves, wave = 32 n-rows.
// K/V for one (b,h) is 256KB; per-XCD working set (b=bid&7 swizzle) is
// 12 heads x 256KB = 3MB -> L2-resident. So LDS staging of K/V was pure
// overhead (guide common-mistake #7): pv2's per-iter chain was
// stage-ds_write -> __syncthreads (full vmcnt drain, 32x/block) -> QK ->
// exp -> Ps -> PV. Now K/V MFMA B-frags are read DIRECTLY from global
// (L2 hits; 4 waves read identical frags -> L1 dedups) and the loop has
// ZERO barriers: waves drift independently, TLP hides L2 latency.
// Only the wave-private Ps transpose stash stays in LDS (10KB/block).
// NOT the R2 failure mode: no forced unroll of the frag-load loop;
// launch_bounds(256,3) caps VGPR (R2's spill came from 12-deep hoisting).
__global__ __launch_bounds__(256, 3)
void attn_pv3(const short* __restrict__ qb, const short* __restrict__ kb,
              const short* __restrict__ vtb, const short* __restrict__ invp,
              short* __restrict__ attn_out) {
    __shared__ __align__(16) short Ps[4][32 * 40];   // per-wave [n][m]

    const int tid = threadIdx.x, lane = tid & 63, wv = tid >> 6;
    const int quad = lane >> 4, l16 = lane & 15;
    const int bid = blockIdx.x;
    const int b = bid & 7;
    const int r = bid >> 3;              // 0..95
    const int n4 = r / 12;               // 0..7 (n128 tile)
    const int h = r - n4 * 12;
    const int nb = n4 << 7;
    const int bh = b * HH + h;

    // Q A-frags for 2 n16-tiles
    bf16x8 aq[2][2];
#pragma unroll
    for (int nt = 0; nt < 2; nt++) {
        const short* qp = qb + (bh << 16) + ((nb + wv * 32 + nt * 16 + l16) << 6) + quad * 8;
        aq[nt][0] = *reinterpret_cast<const bf16x8*>(qp);
        aq[nt][1] = *reinterpret_cast<const bf16x8*>(qp + 32);
    }

    const f32x4 z = (f32x4){0.f, 0.f, 0.f, 0.f};
    f32x4 O[2][4];
#pragma unroll
    for (int nt = 0; nt < 2; nt++)
#pragma unroll
        for (int d = 0; d < 4; d++) O[nt][d] = z;

    // per-lane fragment bases
    const short* kfr = kb  + (bh << 16) + (l16 << 6)  + quad * 8;  // row m=l16, d=quad*8
    const short* vfr = vtb + (bh << 16) + (l16 << 10) + quad * 8;  // row d=l16, m=quad*8

    for (int it = 0; it < 32; it++) {
        const int m0 = it << 5;

        // S + P-stash for two m16-halves x two n-tiles
#pragma unroll
        for (int mh = 0; mh < 2; mh++) {
            const short* kp = kfr + ((m0 + mh * 16) << 6);
            const bf16x8 k0 = *reinterpret_cast<const bf16x8*>(kp);
            const bf16x8 k1 = *reinterpret_cast<const bf16x8*>(kp + 32);
            const int mt = (m0 >> 4) + mh;
#pragma unroll
            for (int nt = 0; nt < 2; nt++) {
                f32x4 s = MFMA16(aq[nt][0], k0, z);
                s = MFMA16(aq[nt][1], k1, s);
                const int ntg = (nb >> 4) + wv * 2 + nt;
                const ushort4 iv = *reinterpret_cast<const ushort4*>(
                    &invp[(((b * 64 + ntg) * 64 + mt) * 64 + lane) * 4]);
                Ps[wv][(nt * 16 + quad * 4 + 0) * 40 + mh * 16 + l16] = f2bf(__builtin_amdgcn_exp2f(s[0] * SCL2E) * bf2f(iv.x));
                Ps[wv][(nt * 16 + quad * 4 + 1) * 40 + mh * 16 + l16] = f2bf(__builtin_amdgcn_exp2f(s[1] * SCL2E) * bf2f(iv.y));
                Ps[wv][(nt * 16 + quad * 4 + 2) * 40 + mh * 16 + l16] = f2bf(__builtin_amdgcn_exp2f(s[2] * SCL2E) * bf2f(iv.z));
                Ps[wv][(nt * 16 + quad * 4 + 3) * 40 + mh * 16 + l16] = f2bf(__builtin_amdgcn_exp2f(s[3] * SCL2E) * bf2f(iv.w));
            }
        }
        __threadfence_block();  // intra-wave cross-lane RAW on Ps (DS in-order)

        // PV
        bf16x8 pa[2];
#pragma unroll
        for (int nt = 0; nt < 2; nt++)
            pa[nt] = *reinterpret_cast<bf16x8*>(&Ps[wv][(nt * 16 + l16) * 40 + quad * 8]);
#pragma unroll
        for (int dch = 0; dch < 4; dch++) {
            const bf16x8 vf = *reinterpret_cast<const bf16x8*>(vfr + (dch << 14) + m0);
#pragma unroll
            for (int nt = 0; nt < 2; nt++)
                O[nt][dch] = MFMA16(pa[nt], vf, O[nt][dch]);
        }
    }

    // epilogue
#pragma unroll
    for (int nt = 0; nt < 2; nt++)
#pragma unroll
        for (int dch = 0; dch < 4; dch++) {
            const int col = h * 64 + dch * 16 + l16;
#pragma unroll
            for (int reg = 0; reg < 4; reg++) {
                const int n = nb + wv * 32 + nt * 16 + quad * 4 + reg;
                attn_out[(size_t)((b << 10) + n) * 768 + col] = f2bf(O[nt][dch][reg]);
            }
        }
}

// ---------- launch ----------
extern "C" void kernel_launch(void* const* d_in, const int* in_sizes, int n_in,
                              void* d_out, int out_size, void* d_ws, size_t ws_size,
                              hipStream_t stream) {
    const float* x     = (const float*)d_in[0];
    const float* w_qkv = (const float*)d_in[1];
    const float* w_out = (const float*)d_in[2];
    const float* b_out = (const float*)d_in[3];
    float* out = (float*)d_out;

    short* xb   = (short*)d_ws;                 // [8192][768]
    short* wT1  = xb  + 8192 * 768;             // [2304][768]
    short* wT2  = wT1 + 2304 * 768;             // [768][768]
    short* qb   = wT2 + 768 * 768;              // [b][h][n][d]
    short* kb   = qb  + 96 * 65536;
    short* vtb  = kb  + 96 * 65536;             // [b][h][d][n]
    short* attn = vtb + 96 * 65536;             // [8192][768]
    short* invp = attn + 8192 * 768;            // [b][nt][mt][lane][4]

    cast_to_bf16<<<6144, 256, 0, stream>>>(x, xb, (8192 * 768) / 4);
    transpose_cast<<<(2304 * 768) / 256, 256, 0, stream>>>(w_qkv, wT1, 768, 2304);
    transpose_cast<<<(768 * 768) / 256, 256, 0, stream>>>(w_out, wT2, 768, 768);

    // 1D grids, XCD-swizzled decode inside the kernel.
    gemm128<0><<<1152, 256, 0, stream>>>(
        xb, wT1, 768, qb, kb, vtb, nullptr, nullptr);

    attn_den5<<<512, 512, 0, stream>>>(qb, kb, invp);
    attn_pv3<<<768, 256, 0, stream>>>(qb, kb, vtb, invp, attn);

    gemm128<1><<<384, 256, 0, stream>>>(
        attn, wT2, 768, nullptr, nullptr, nullptr, out, b_out);
}

// Round 9
// 229.802 us; speedup vs baseline: 1.2571x; 1.2571x over previous
//
#include <hip/hip_runtime.h>

// ---------- common types ----------
typedef float  f32x4  __attribute__((ext_vector_type(4)));
typedef short  bf16x8 __attribute__((ext_vector_type(8)));

#define MFMA16(a, b, c) __builtin_amdgcn_mfma_f32_16x16x32_bf16((a), (b), (c), 0, 0, 0)

// global -> LDS direct DMA, 16B per lane. LDS dest is wave-uniform base +
// lane*16 (linear); global src is per-lane.
#define GLL16(g, l) __builtin_amdgcn_global_load_lds(                      \
    (const __attribute__((address_space(1))) void*)(g),                    \
    (__attribute__((address_space(3))) void*)(l), 16, 0, 0)

__device__ __forceinline__ short f2bf(float f) {
    union { float f; unsigned u; } a; a.f = f;
    unsigned r = a.u + 0x7fffu + ((a.u >> 16) & 1u);  // RNE
    return (short)(r >> 16);
}
__device__ __forceinline__ float bf2f(unsigned short u) {
    union { unsigned u; float f; } a; a.u = ((unsigned)u) << 16; return a.f;
}

// sizes
#define Bb   8
#define Nn   1024
#define DIM  768
#define HH   12
#define HD   64
#define INNER 768
#define SCALE 0.125f
// SCALE * log2(e): exp(s*SCALE) == exp2(s*SCL2E)
#define SCL2E 0.18033688011112042f

// ---------- prep kernels ----------
__global__ void cast_to_bf16(const float* __restrict__ in, short* __restrict__ out, int n4) {
    int i = blockIdx.x * 256 + threadIdx.x;
    if (i >= n4) return;
    float4 f = reinterpret_cast<const float4*>(in)[i];
    unsigned lo = (unsigned)(unsigned short)f2bf(f.x) | ((unsigned)(unsigned short)f2bf(f.y) << 16);
    unsigned hi = (unsigned)(unsigned short)f2bf(f.z) | ((unsigned)(unsigned short)f2bf(f.w) << 16);
    reinterpret_cast<uint2*>(out)[i] = make_uint2(lo, hi);
}

// ---------- tiled transpose+cast: wt[c][k] = bf16(w[k][c]) ----------
// R8 finding: the naive per-element transpose read w at stride cols*4B ->
// every 4B pulled a distinct 64B line, re-fetched by ~16 c-blocks
// (~160MB of line traffic for 10MB of matrices). 64x64 LDS tile:
// coalesced 256B reads, +1-pad (65-float rows -> (tx+j)%32 banks, 2-way
// = free), coalesced 128B bf16 writes. rows, cols both divisible by 64.
__global__ __launch_bounds__(256, 8)
void transpose_cast_t(const float* __restrict__ w, short* __restrict__ wt,
                      int rows, int cols) {
    __shared__ float t[64][65];
    const int ntx = cols >> 6;
    const int bx = blockIdx.x % ntx;       // c-tile
    const int by = blockIdx.x / ntx;       // k-tile
    const int c0 = bx << 6, k0 = by << 6;
    const int tx = threadIdx.x & 63, ty = threadIdx.x >> 6;   // ty 0..3
#pragma unroll
    for (int j = 0; j < 64; j += 4)
        t[ty + j][tx] = w[(size_t)(k0 + ty + j) * cols + c0 + tx];
    __syncthreads();
#pragma unroll
    for (int j = 0; j < 64; j += 4)
        wt[(size_t)(c0 + ty + j) * rows + k0 + tx] = f2bf(t[tx][ty + j]);
}

// ---------- GEMM v5 (R6, proven 57.4us): 3-buf counted-vmcnt + XCD swizzle ----------
// C[M,N] = A[M,K] @ Bt[N,K]^T. 128x128 tile, BK=32, 4 waves (2x2, 64x64 each).
// 3 LDS buffers, stage distance 2, counted vmcnt(4), raw s_barrier,
// lgkmcnt(0)+sched_barrier before MFMA, setprio around MFMA.
// XCD decode: y=(bid&7)*8+((bid>>3)&7), x=bid>>6 -> 8 co-resident blocks
// per XCD share one B-panel + an 8-row A-band (~1.8MB L2 working set).
// R7 lesson: 256x128 tile regressed (69us); 128^2 is the proven structure.
#define STAGE(ksv, bv)                                                      \
  { const int kc_ = (ksv) << 5;                                             \
    GLL16(A  + aoff + kc_,                  &As[bv][lch]);                  \
    GLL16(A  + aoff + (size_t)64 * K + kc_, &As[bv][2048 + lch]);           \
    GLL16(Bt + boff + kc_,                  &Bs[bv][lch]);                  \
    GLL16(Bt + boff + (size_t)64 * K + kc_, &Bs[bv][2048 + lch]); }

#define PHASE(VM, DO_STAGE)                                                 \
  {                                                                         \
    bf16x8 af[4], bfr[4];                                                   \
    _Pragma("unroll") for (int t = 0; t < 4; t++)                           \
      af[t] = *reinterpret_cast<const bf16x8*>(                             \
          &As[bi][(wrow * 64 + t * 16 + l16) * 32 + swo]);                  \
    _Pragma("unroll") for (int t = 0; t < 4; t++)                           \
      bfr[t] = *reinterpret_cast<const bf16x8*>(                            \
          &Bs[bi][(wcol * 64 + t * 16 + l16) * 32 + swo]);                  \
    if (DO_STAGE) { STAGE(ks + 2, bn); }                                    \
    asm volatile("s_waitcnt vmcnt(" #VM ")" ::: "memory");                  \
    __builtin_amdgcn_s_barrier();                                           \
    asm volatile("s_waitcnt lgkmcnt(0)" ::: "memory");                      \
    __builtin_amdgcn_sched_barrier(0);                                      \
    __builtin_amdgcn_s_setprio(1);                                          \
    _Pragma("unroll") for (int rt = 0; rt < 4; rt++)                        \
      _Pragma("unroll") for (int ct = 0; ct < 4; ct++)                      \
        acc[rt][ct] = MFMA16(af[rt], bfr[ct], acc[rt][ct]);                 \
    __builtin_amdgcn_s_setprio(0);                                          \
    __builtin_amdgcn_s_barrier();                                           \
  }

template <int MODE>
__global__ __launch_bounds__(256, 3)
void gemm128(const short* __restrict__ A, const short* __restrict__ Bt, int K,
             short* __restrict__ qb, short* __restrict__ kb, short* __restrict__ vtb,
             float* __restrict__ outp, const float* __restrict__ bias) {
    __shared__ __align__(16) short As[3][128 * 32];
    __shared__ __align__(16) short Bs[3][128 * 32];

    const int tid  = threadIdx.x;
    const int lane = tid & 63, wv = tid >> 6;
    const int wrow = wv >> 1, wcol = wv & 1;
    const int quad = lane >> 4, l16 = lane & 15;

    const int bid = blockIdx.x;
    const int m0 = (((bid & 7) << 3) | ((bid >> 3) & 7)) << 7;
    const int n0 = (bid >> 6) << 7;

    const int row64 = (wv << 4) + (lane >> 2);
    const int gu = (lane & 3) ^ ((lane >> 3) & 3);
    const size_t aoff = (size_t)(m0 + row64) * K + gu * 8;
    const size_t boff = (size_t)(n0 + row64) * K + gu * 8;
    const int lch = wv * 512;

    f32x4 acc[4][4];
#pragma unroll
    for (int i = 0; i < 4; i++)
#pragma unroll
        for (int j = 0; j < 4; j++) acc[i][j] = (f32x4){0.f, 0.f, 0.f, 0.f};

    const int swo = (quad ^ ((l16 >> 1) & 3)) * 8;

    const int NK = K >> 5;  // 24

    STAGE(0, 0);
    STAGE(1, 1);
    asm volatile("s_waitcnt vmcnt(4)" ::: "memory");
    __builtin_amdgcn_s_barrier();

    int bi = 0, bn = 2;
    int ks = 0;
    for (; ks < NK - 2; ks++) {
        PHASE(4, true);
        bi = (bi == 2) ? 0 : bi + 1;
        bn = (bn == 2) ? 0 : bn + 1;
    }
    PHASE(0, false);
    bi = (bi == 2) ? 0 : bi + 1;
    PHASE(0, false);

    // epilogue: C/D layout col=lane&15, row=quad*4+reg
#pragma unroll
    for (int rt = 0; rt < 4; rt++) {
#pragma unroll
        for (int ct = 0; ct < 4; ct++) {
            const int c = n0 + wcol * 64 + ct * 16 + l16;
#pragma unroll
            for (int reg = 0; reg < 4; reg++) {
                const int r = m0 + wrow * 64 + rt * 16 + quad * 4 + reg;
                const float v = acc[rt][ct][reg];
                if (MODE == 0) {
                    const int b = r >> 10, n = r & 1023;
                    const int which = (c >= 1536) ? 2 : (c >= 768 ? 1 : 0);
                    const int cc = c - which * 768;
                    const int h = cc >> 6, d = cc & 63;
                    const int bh = b * HH + h;
                    const short bv = f2bf(v);
                    if (which == 0)      qb[(bh << 16) + (n << 6) + d] = bv;
                    else if (which == 1) kb[(bh << 16) + (n << 6) + d] = bv;
                    else                 vtb[(bh << 16) + (d << 10) + n] = bv;
                } else {
                    outp[(size_t)r * 768 + c] = v + bias[c];
                }
            }
        }
    }
}

// ---------- attention pass 1 v5: gll + double-buffer + XOR swizzle ----------
__global__ __launch_bounds__(512, 4)
void attn_den5(const short* __restrict__ qb, const short* __restrict__ kb,
               short* __restrict__ invp) {
    __shared__ __align__(16) short Qs[2][128 * 64];
    __shared__ __align__(16) short Ks[2][128 * 64];

    const int tid = threadIdx.x, lane = tid & 63, wv = tid >> 6;  // wv 0..7
    const int wrow = wv >> 2, wcol = wv & 3;                      // 2 x 4
    const int quad = lane >> 4, l16 = lane & 15;
    const int bid = blockIdx.x;
    const int b = bid & 7;
    const int nmt = bid >> 3;            // 0..63
    const int n0 = (nmt >> 3) << 7;      // n128 base
    const int m0 = (nmt & 7) << 7;       // m128 base

    const int r8 = lane >> 3;                 // 0..7, == row&7
    const int gu = (lane & 7) ^ r8;           // pre-swizzled global unit
    const int qo0 = (n0 + wv * 8 + r8) * 64 + gu * 8;   // shorts
    const int qo1 = qo0 + 64 * 64;                      // +64 rows
    const int ko0 = (m0 + wv * 8 + r8) * 64 + gu * 8;
    const int ko1 = ko0 + 64 * 64;
    const int lc0 = wv * 512;                 // wave LDS chunk, it=0 (shorts)
    const int lc1 = 4096 + wv * 512;          // it=1

    f32x4 den[4][2];
#pragma unroll
    for (int i = 0; i < 4; i++)
#pragma unroll
        for (int j = 0; j < 2; j++) den[i][j] = (f32x4){0.f, 0.f, 0.f, 0.f};
    const f32x4 z = (f32x4){0.f, 0.f, 0.f, 0.f};

    {
        const short* qh = qb + ((size_t)(b * HH) << 16);
        const short* kh = kb + ((size_t)(b * HH) << 16);
        GLL16(qh + qo0, &Qs[0][lc0]);
        GLL16(qh + qo1, &Qs[0][lc1]);
        GLL16(kh + ko0, &Ks[0][lc0]);
        GLL16(kh + ko1, &Ks[0][lc1]);
    }

    for (int h = 0; h < HH; h++) {
        asm volatile("s_waitcnt vmcnt(0)" ::: "memory");  // this head's DMA landed
        __syncthreads();                                  // all waves see it
        if (h < HH - 1) {
            const int pn = (h + 1) & 1;
            const short* qh = qb + ((size_t)(b * HH + h + 1) << 16);
            const short* kh = kb + ((size_t)(b * HH + h + 1) << 16);
            GLL16(qh + qo0, &Qs[pn][lc0]);
            GLL16(qh + qo1, &Qs[pn][lc1]);
            GLL16(kh + ko0, &Ks[pn][lc0]);
            GLL16(kh + ko1, &Ks[pn][lc1]);
        }
        const int pb = h & 1;
        const int sw0 = (quad ^ (l16 & 7)) * 8;

        bf16x8 aq[4][2], bk[2][2];
#pragma unroll
        for (int t = 0; t < 4; t++) {
            const int row = wrow * 64 + t * 16 + l16;
            aq[t][0] = *reinterpret_cast<bf16x8*>(&Qs[pb][row * 64 + sw0]);
            aq[t][1] = *reinterpret_cast<bf16x8*>(&Qs[pb][row * 64 + (sw0 ^ 32)]);
        }
#pragma unroll
        for (int t = 0; t < 2; t++) {
            const int row = wcol * 32 + t * 16 + l16;
            bk[t][0] = *reinterpret_cast<bf16x8*>(&Ks[pb][row * 64 + sw0]);
            bk[t][1] = *reinterpret_cast<bf16x8*>(&Ks[pb][row * 64 + (sw0 ^ 32)]);
        }
#pragma unroll
        for (int nt = 0; nt < 4; nt++)
#pragma unroll
            for (int mt = 0; mt < 2; mt++) {
                f32x4 s = MFMA16(aq[nt][0], bk[mt][0], z);
                s = MFMA16(aq[nt][1], bk[mt][1], s);
#pragma unroll
                for (int r = 0; r < 4; r++)
                    den[nt][mt][r] += __builtin_amdgcn_exp2f(s[r] * SCL2E);
            }
    }

#pragma unroll
    for (int nt = 0; nt < 4; nt++)
#pragma unroll
        for (int mt = 0; mt < 2; mt++) {
            const int ntg = (n0 >> 4) + wrow * 4 + nt;
            const int mtg = (m0 >> 4) + wcol * 2 + mt;
            ushort4 o;
            o.x = (unsigned short)f2bf(1.0f / den[nt][mt][0]);
            o.y = (unsigned short)f2bf(1.0f / den[nt][mt][1]);
            o.z = (unsigned short)f2bf(1.0f / den[nt][mt][2]);
            o.w = (unsigned short)f2bf(1.0f / den[nt][mt][3]);
            *reinterpret_cast<ushort4*>(&invp[(((b * 64 + ntg) * 64 + mtg) * 64 + lane) * 4]) = o;
        }
}

// ---------- attention pass 2 v2 (restored, proven ~67us) ----------
// Block = (b, h, n128): 768 blocks (3/CU), 4 waves, wave = 32 n-rows.
// K/V double-buffered in LDS -> ONE barrier per m32-iter. P transposed
// through wave-private LDS stash (intra-wave, no barrier).
// R8 lesson: removing K/V LDS (global-direct frags) regressed 67->107us —
// per-iter dependent L2 loads + no cross-wave reuse amortization.
__global__ __launch_bounds__(256, 4)
void attn_pv2(const short* __restrict__ qb, const short* __restrict__ kb,
              const short* __restrict__ vtb, const short* __restrict__ invp,
              short* __restrict__ attn_out) {
    __shared__ __align__(16) short Ks[2][32 * 72];   // [m][d]
    __shared__ __align__(16) short Vs[2][64 * 40];   // [d][m]
    __shared__ __align__(16) short Ps[4][32 * 40];   // per-wave [n][m]

    const int tid = threadIdx.x, lane = tid & 63, wv = tid >> 6;
    const int quad = lane >> 4, l16 = lane & 15;
    const int bid = blockIdx.x;
    const int b = bid & 7;
    const int r = bid >> 3;              // 0..95
    const int n4 = r / 12;               // 0..7 (n128 tile)
    const int h = r - n4 * 12;
    const int nb = n4 << 7;
    const int bh = b * HH + h;

    bf16x8 aq[2][2];
#pragma unroll
    for (int nt = 0; nt < 2; nt++) {
        const short* qp = qb + (bh << 16) + ((nb + wv * 32 + nt * 16 + l16) << 6) + quad * 8;
        aq[nt][0] = *reinterpret_cast<const bf16x8*>(qp);
        aq[nt][1] = *reinterpret_cast<const bf16x8*>(qp + 32);
    }

    const f32x4 z = (f32x4){0.f, 0.f, 0.f, 0.f};
    f32x4 O[2][4];
#pragma unroll
    for (int nt = 0; nt < 2; nt++)
#pragma unroll
        for (int d = 0; d < 4; d++) O[nt][d] = z;

    const int krow = tid >> 3, koff = (tid & 7) * 8;   // K: 32 rows x 128B
    const int vrow = tid >> 2, voff = (tid & 3) * 8;   // V: 64 rows x 64B

    uint4 kreg = *reinterpret_cast<const uint4*>(kb + (bh << 16) + (krow << 6) + koff);
    uint4 vreg = *reinterpret_cast<const uint4*>(vtb + (bh << 16) + (vrow << 10) + voff);

    for (int it = 0; it < 32; it++) {
        const int p = it & 1;
        *reinterpret_cast<uint4*>(&Ks[p][krow * 72 + koff]) = kreg;
        *reinterpret_cast<uint4*>(&Vs[p][vrow * 40 + voff]) = vreg;
        __syncthreads();
        if (it < 31) {
            const int m1 = (it + 1) << 5;
            kreg = *reinterpret_cast<const uint4*>(kb + (bh << 16) + ((m1 + krow) << 6) + koff);
            vreg = *reinterpret_cast<const uint4*>(vtb + (bh << 16) + (vrow << 10) + m1 + voff);
        }
        const int m0 = it << 5;

#pragma unroll
        for (int mh = 0; mh < 2; mh++) {
            const bf16x8 k0 = *reinterpret_cast<bf16x8*>(&Ks[p][(mh * 16 + l16) * 72 + quad * 8]);
            const bf16x8 k1 = *reinterpret_cast<bf16x8*>(&Ks[p][(mh * 16 + l16) * 72 + quad * 8 + 32]);
            const int mt = (m0 >> 4) + mh;
#pragma unroll
            for (int nt = 0; nt < 2; nt++) {
                f32x4 s = MFMA16(aq[nt][0], k0, z);
                s = MFMA16(aq[nt][1], k1, s);
                const int ntg = (nb >> 4) + wv * 2 + nt;
                const ushort4 iv = *reinterpret_cast<const ushort4*>(
                    &invp[(((b * 64 + ntg) * 64 + mt) * 64 + lane) * 4]);
                Ps[wv][(nt * 16 + quad * 4 + 0) * 40 + mh * 16 + l16] = f2bf(__expf(s[0] * SCALE) * bf2f(iv.x));
                Ps[wv][(nt * 16 + quad * 4 + 1) * 40 + mh * 16 + l16] = f2bf(__expf(s[1] * SCALE) * bf2f(iv.y));
                Ps[wv][(nt * 16 + quad * 4 + 2) * 40 + mh * 16 + l16] = f2bf(__expf(s[2] * SCALE) * bf2f(iv.z));
                Ps[wv][(nt * 16 + quad * 4 + 3) * 40 + mh * 16 + l16] = f2bf(__expf(s[3] * SCALE) * bf2f(iv.w));
            }
        }
        __threadfence_block();  // intra-wave cross-lane RAW on Ps

        bf16x8 pa[2];
#pragma unroll
        for (int nt = 0; nt < 2; nt++)
            pa[nt] = *reinterpret_cast<bf16x8*>(&Ps[wv][(nt * 16 + l16) * 40 + quad * 8]);
#pragma unroll
        for (int dch = 0; dch < 4; dch++) {
            const bf16x8 vf = *reinterpret_cast<bf16x8*>(&Vs[p][(dch * 16 + l16) * 40 + quad * 8]);
#pragma unroll
            for (int nt = 0; nt < 2; nt++)
                O[nt][dch] = MFMA16(pa[nt], vf, O[nt][dch]);
        }
    }

#pragma unroll
    for (int nt = 0; nt < 2; nt++)
#pragma unroll
        for (int dch = 0; dch < 4; dch++) {
            const int col = h * 64 + dch * 16 + l16;
#pragma unroll
            for (int reg = 0; reg < 4; reg++) {
                const int n = nb + wv * 32 + nt * 16 + quad * 4 + reg;
                attn_out[(size_t)((b << 10) + n) * 768 + col] = f2bf(O[nt][dch][reg]);
            }
        }
}

// ---------- launch ----------
extern "C" void kernel_launch(void* const* d_in, const int* in_sizes, int n_in,
                              void* d_out, int out_size, void* d_ws, size_t ws_size,
                              hipStream_t stream) {
    const float* x     = (const float*)d_in[0];
    const float* w_qkv = (const float*)d_in[1];
    const float* w_out = (const float*)d_in[2];
    const float* b_out = (const float*)d_in[3];
    float* out = (float*)d_out;

    short* xb   = (short*)d_ws;                 // [8192][768]
    short* wT1  = xb  + 8192 * 768;             // [2304][768]
    short* wT2  = wT1 + 2304 * 768;             // [768][768]
    short* qb   = wT2 + 768 * 768;              // [b][h][n][d]
    short* kb   = qb  + 96 * 65536;
    short* vtb  = kb  + 96 * 65536;             // [b][h][d][n]
    short* attn = vtb + 96 * 65536;             // [8192][768]
    short* invp = attn + 8192 * 768;            // [b][nt][mt][lane][4]

    cast_to_bf16<<<6144, 256, 0, stream>>>(x, xb, (8192 * 768) / 4);
    // tiled transposes: (rows/64)*(cols/64) blocks
    transpose_cast_t<<<(768 / 64) * (2304 / 64), 256, 0, stream>>>(w_qkv, wT1, 768, 2304);
    transpose_cast_t<<<(768 / 64) * (768 / 64), 256, 0, stream>>>(w_out, wT2, 768, 768);

    // 1D grids, XCD-swizzled decode inside the kernel.
    gemm128<0><<<1152, 256, 0, stream>>>(
        xb, wT1, 768, qb, kb, vtb, nullptr, nullptr);

    attn_den5<<<512, 512, 0, stream>>>(qb, kb, invp);
    attn_pv2<<<768, 256, 0, stream>>>(qb, kb, vtb, invp, attn);

    gemm128<1><<<384, 256, 0, stream>>>(
        attn, wT2, 768, nullptr, nullptr, nullptr, out, b_out);
}

// Round 10
// 224.299 us; speedup vs baseline: 1.2879x; 1.0245x over previous
//
#include <hip/hip_runtime.h>

// ---------- common types ----------
typedef float  f32x4  __attribute__((ext_vector_type(4)));
typedef short  bf16x8 __attribute__((ext_vector_type(8)));

#define MFMA16(a, b, c) __builtin_amdgcn_mfma_f32_16x16x32_bf16((a), (b), (c), 0, 0, 0)

// global -> LDS direct DMA, 16B per lane. LDS dest is wave-uniform base +
// lane*16 (linear); global src is per-lane.
#define GLL16(g, l) __builtin_amdgcn_global_load_lds(                      \
    (const __attribute__((address_space(1))) void*)(g),                    \
    (__attribute__((address_space(3))) void*)(l), 16, 0, 0)

__device__ __forceinline__ short f2bf(float f) {
    union { float f; unsigned u; } a; a.f = f;
    unsigned r = a.u + 0x7fffu + ((a.u >> 16) & 1u);  // RNE
    return (short)(r >> 16);
}
__device__ __forceinline__ float bf2f(unsigned short u) {
    union { unsigned u; float f; } a; a.u = ((unsigned)u) << 16; return a.f;
}

// sizes
#define Bb   8
#define Nn   1024
#define DIM  768
#define HH   12
#define HD   64
#define INNER 768
#define SCALE 0.125f
// SCALE * log2(e): exp(s*SCALE) == exp2(s*SCL2E)
#define SCL2E 0.18033688011112042f

// ---------- fused prep: cast x + transpose both weight matrices ----------
// One launch instead of three (saves 2 inter-dispatch gaps).
// bid < 6144: bf16-cast of x (6144*256*4 = 8192*768 floats exactly).
// 6144..6575: 64x64 transpose tile of w_qkv (12*36 = 432 tiles).
// 6576..6719: 64x64 transpose tile of w_out (12*12 = 144 tiles).
// Transpose: coalesced 256B reads, +1-pad LDS (2-way bank = free),
// coalesced 128B bf16 writes (R9-proven).
__global__ __launch_bounds__(256, 8)
void prep(const float* __restrict__ x, short* __restrict__ xb,
          const float* __restrict__ w_qkv, short* __restrict__ wT1,
          const float* __restrict__ w_out, short* __restrict__ wT2) {
    __shared__ float t[64][65];
    const int bid = blockIdx.x;
    if (bid < 6144) {
        const int i = bid * 256 + threadIdx.x;
        float4 f = reinterpret_cast<const float4*>(x)[i];
        unsigned lo = (unsigned)(unsigned short)f2bf(f.x) | ((unsigned)(unsigned short)f2bf(f.y) << 16);
        unsigned hi = (unsigned)(unsigned short)f2bf(f.z) | ((unsigned)(unsigned short)f2bf(f.w) << 16);
        reinterpret_cast<uint2*>(xb)[i] = make_uint2(lo, hi);
        return;
    }
    const float* w; short* wt; int cols, tix;
    if (bid < 6576) { w = w_qkv; wt = wT1; cols = 2304; tix = bid - 6144; }
    else            { w = w_out; wt = wT2; cols = 768;  tix = bid - 6576; }
    const int rows = 768;
    const int ntx = cols >> 6;
    const int bx = tix % ntx;              // c-tile
    const int by = tix / ntx;              // k-tile
    const int c0 = bx << 6, k0 = by << 6;
    const int tx = threadIdx.x & 63, ty = threadIdx.x >> 6;   // ty 0..3
#pragma unroll
    for (int j = 0; j < 64; j += 4)
        t[ty + j][tx] = w[(size_t)(k0 + ty + j) * cols + c0 + tx];
    __syncthreads();
#pragma unroll
    for (int j = 0; j < 64; j += 4)
        wt[(size_t)(c0 + ty + j) * rows + k0 + tx] = f2bf(t[tx][ty + j]);
}

// ---------- GEMM v5 (R6, proven 57.4us): 3-buf counted-vmcnt + XCD swizzle ----------
// C[M,N] = A[M,K] @ Bt[N,K]^T. 128x128 tile, BK=32, 4 waves (2x2, 64x64 each).
// 3 LDS buffers, stage distance 2, counted vmcnt(4), raw s_barrier,
// lgkmcnt(0)+sched_barrier before MFMA, setprio around MFMA.
// XCD decode: y=(bid&7)*8+((bid>>3)&7), x=bid>>6 -> 8 co-resident blocks
// per XCD share one B-panel + an 8-row A-band (~1.8MB L2 working set).
#define STAGE(ksv, bv)                                                      \
  { const int kc_ = (ksv) << 5;                                             \
    GLL16(A  + aoff + kc_,                  &As[bv][lch]);                  \
    GLL16(A  + aoff + (size_t)64 * K + kc_, &As[bv][2048 + lch]);           \
    GLL16(Bt + boff + kc_,                  &Bs[bv][lch]);                  \
    GLL16(Bt + boff + (size_t)64 * K + kc_, &Bs[bv][2048 + lch]); }

#define PHASE(VM, DO_STAGE)                                                 \
  {                                                                         \
    bf16x8 af[4], bfr[4];                                                   \
    _Pragma("unroll") for (int t = 0; t < 4; t++)                           \
      af[t] = *reinterpret_cast<const bf16x8*>(                             \
          &As[bi][(wrow * 64 + t * 16 + l16) * 32 + swo]);                  \
    _Pragma("unroll") for (int t = 0; t < 4; t++)                           \
      bfr[t] = *reinterpret_cast<const bf16x8*>(                            \
          &Bs[bi][(wcol * 64 + t * 16 + l16) * 32 + swo]);                  \
    if (DO_STAGE) { STAGE(ks + 2, bn); }                                    \
    asm volatile("s_waitcnt vmcnt(" #VM ")" ::: "memory");                  \
    __builtin_amdgcn_s_barrier();                                           \
    asm volatile("s_waitcnt lgkmcnt(0)" ::: "memory");                      \
    __builtin_amdgcn_sched_barrier(0);                                      \
    __builtin_amdgcn_s_setprio(1);                                          \
    _Pragma("unroll") for (int rt = 0; rt < 4; rt++)                        \
      _Pragma("unroll") for (int ct = 0; ct < 4; ct++)                      \
        acc[rt][ct] = MFMA16(af[rt], bfr[ct], acc[rt][ct]);                 \
    __builtin_amdgcn_s_setprio(0);                                          \
    __builtin_amdgcn_s_barrier();                                           \
  }

template <int MODE>
__global__ __launch_bounds__(256, 3)
void gemm128(const short* __restrict__ A, const short* __restrict__ Bt, int K,
             short* __restrict__ qb, short* __restrict__ kb, short* __restrict__ vtb,
             float* __restrict__ outp, const float* __restrict__ bias) {
    __shared__ __align__(16) short As[3][128 * 32];
    __shared__ __align__(16) short Bs[3][128 * 32];

    const int tid  = threadIdx.x;
    const int lane = tid & 63, wv = tid >> 6;
    const int wrow = wv >> 1, wcol = wv & 1;
    const int quad = lane >> 4, l16 = lane & 15;

    const int bid = blockIdx.x;
    const int m0 = (((bid & 7) << 3) | ((bid >> 3) & 7)) << 7;
    const int n0 = (bid >> 6) << 7;

    const int row64 = (wv << 4) + (lane >> 2);
    const int gu = (lane & 3) ^ ((lane >> 3) & 3);
    const size_t aoff = (size_t)(m0 + row64) * K + gu * 8;
    const size_t boff = (size_t)(n0 + row64) * K + gu * 8;
    const int lch = wv * 512;

    f32x4 acc[4][4];
#pragma unroll
    for (int i = 0; i < 4; i++)
#pragma unroll
        for (int j = 0; j < 4; j++) acc[i][j] = (f32x4){0.f, 0.f, 0.f, 0.f};

    const int swo = (quad ^ ((l16 >> 1) & 3)) * 8;

    const int NK = K >> 5;  // 24

    STAGE(0, 0);
    STAGE(1, 1);
    asm volatile("s_waitcnt vmcnt(4)" ::: "memory");
    __builtin_amdgcn_s_barrier();

    int bi = 0, bn = 2;
    int ks = 0;
    for (; ks < NK - 2; ks++) {
        PHASE(4, true);
        bi = (bi == 2) ? 0 : bi + 1;
        bn = (bn == 2) ? 0 : bn + 1;
    }
    PHASE(0, false);
    bi = (bi == 2) ? 0 : bi + 1;
    PHASE(0, false);

    // epilogue: C/D layout col=lane&15, row=quad*4+reg
#pragma unroll
    for (int rt = 0; rt < 4; rt++) {
#pragma unroll
        for (int ct = 0; ct < 4; ct++) {
            const int c = n0 + wcol * 64 + ct * 16 + l16;
#pragma unroll
            for (int reg = 0; reg < 4; reg++) {
                const int r = m0 + wrow * 64 + rt * 16 + quad * 4 + reg;
                const float v = acc[rt][ct][reg];
                if (MODE == 0) {
                    const int b = r >> 10, n = r & 1023;
                    const int which = (c >= 1536) ? 2 : (c >= 768 ? 1 : 0);
                    const int cc = c - which * 768;
                    const int h = cc >> 6, d = cc & 63;
                    const int bh = b * HH + h;
                    const short bv = f2bf(v);
                    if (which == 0)      qb[(bh << 16) + (n << 6) + d] = bv;
                    else if (which == 1) kb[(bh << 16) + (n << 6) + d] = bv;
                    else                 vtb[(bh << 16) + (d << 10) + n] = bv;
                } else {
                    outp[(size_t)r * 768 + c] = v + bias[c];
                }
            }
        }
    }
}

// ---------- out-GEMM: 128x64 tile, 768 blocks (3/CU) ----------
// R9 analysis: MODE1 at 128^2 had only 384 blocks = 1.5 blocks/CU -> half
// the CUs ran ONE 4-wave block, every phase's latency fully exposed.
// 128x64 tile doubles the grid to 768 (3/CU). Same proven 3-buffer
// counted-vmcnt schedule; A = 2 GLLs, B = 1 GLL per stage -> vmcnt(3).
// Same swizzle algebra (row bases all ==0 mod 8). XCD decode bijective
// over 768 (64 mt x 12 nt).
#define OSTAGE(ksv, bv)                                                     \
  { const int kc_ = (ksv) << 5;                                             \
    GLL16(A  + aoff + kc_,                  &As[bv][lch]);                  \
    GLL16(A  + aoff + (size_t)64 * K + kc_, &As[bv][2048 + lch]);           \
    GLL16(Bt + boff + kc_,                  &Bs[bv][lch]); }

#define OPHASE(VM, DO_STAGE)                                                \
  {                                                                         \
    bf16x8 af[4], bfr[2];                                                   \
    _Pragma("unroll") for (int t = 0; t < 4; t++)                           \
      af[t] = *reinterpret_cast<const bf16x8*>(                             \
          &As[bi][(wrow * 64 + t * 16 + l16) * 32 + swo]);                  \
    _Pragma("unroll") for (int t = 0; t < 2; t++)                           \
      bfr[t] = *reinterpret_cast<const bf16x8*>(                            \
          &Bs[bi][(wcol * 32 + t * 16 + l16) * 32 + swo]);                  \
    if (DO_STAGE) { OSTAGE(ks + 2, bn); }                                   \
    asm volatile("s_waitcnt vmcnt(" #VM ")" ::: "memory");                  \
    __builtin_amdgcn_s_barrier();                                           \
    asm volatile("s_waitcnt lgkmcnt(0)" ::: "memory");                      \
    __builtin_amdgcn_sched_barrier(0);                                      \
    __builtin_amdgcn_s_setprio(1);                                          \
    _Pragma("unroll") for (int rt = 0; rt < 4; rt++)                        \
      _Pragma("unroll") for (int ct = 0; ct < 2; ct++)                      \
        acc[rt][ct] = MFMA16(af[rt], bfr[ct], acc[rt][ct]);                 \
    __builtin_amdgcn_s_setprio(0);                                          \
    __builtin_amdgcn_s_barrier();                                           \
  }

__global__ __launch_bounds__(256, 4)
void gemm_o(const short* __restrict__ A, const short* __restrict__ Bt, int K,
            float* __restrict__ outp, const float* __restrict__ bias) {
    __shared__ __align__(16) short As[3][128 * 32];   // 8KB each
    __shared__ __align__(16) short Bs[3][64 * 32];    // 4KB each

    const int tid  = threadIdx.x;
    const int lane = tid & 63, wv = tid >> 6;
    const int wrow = wv >> 1, wcol = wv & 1;          // 2x2 waves, 64x32 each
    const int quad = lane >> 4, l16 = lane & 15;

    const int bid = blockIdx.x;                        // 0..767
    const int m0 = (((bid & 7) << 3) | ((bid >> 3) & 7)) << 7;   // 64 mt
    const int n0 = (bid >> 6) << 6;                    // 12 nt x 64 cols

    const int row64 = (wv << 4) + (lane >> 2);         // 0..63
    const int gu = (lane & 3) ^ ((lane >> 3) & 3);
    const size_t aoff = (size_t)(m0 + row64) * K + gu * 8;
    const size_t boff = (size_t)(n0 + row64) * K + gu * 8;
    const int lch = wv * 512;

    f32x4 acc[4][2];
#pragma unroll
    for (int i = 0; i < 4; i++)
#pragma unroll
        for (int j = 0; j < 2; j++) acc[i][j] = (f32x4){0.f, 0.f, 0.f, 0.f};

    const int swo = (quad ^ ((l16 >> 1) & 3)) * 8;

    const int NK = K >> 5;  // 24

    OSTAGE(0, 0);
    OSTAGE(1, 1);
    asm volatile("s_waitcnt vmcnt(3)" ::: "memory");   // stage 0 landed
    __builtin_amdgcn_s_barrier();

    int bi = 0, bn = 2;
    int ks = 0;
    for (; ks < NK - 2; ks++) {
        OPHASE(3, true);
        bi = (bi == 2) ? 0 : bi + 1;
        bn = (bn == 2) ? 0 : bn + 1;
    }
    OPHASE(0, false);
    bi = (bi == 2) ? 0 : bi + 1;
    OPHASE(0, false);

#pragma unroll
    for (int rt = 0; rt < 4; rt++) {
#pragma unroll
        for (int ct = 0; ct < 2; ct++) {
            const int c = n0 + wcol * 32 + ct * 16 + l16;
#pragma unroll
            for (int reg = 0; reg < 4; reg++) {
                const int r = m0 + wrow * 64 + rt * 16 + quad * 4 + reg;
                outp[(size_t)r * 768 + c] = acc[rt][ct][reg] + bias[c];
            }
        }
    }
}

// ---------- attention pass 1 v5: gll + double-buffer + XOR swizzle ----------
__global__ __launch_bounds__(512, 4)
void attn_den5(const short* __restrict__ qb, const short* __restrict__ kb,
               short* __restrict__ invp) {
    __shared__ __align__(16) short Qs[2][128 * 64];
    __shared__ __align__(16) short Ks[2][128 * 64];

    const int tid = threadIdx.x, lane = tid & 63, wv = tid >> 6;  // wv 0..7
    const int wrow = wv >> 2, wcol = wv & 3;                      // 2 x 4
    const int quad = lane >> 4, l16 = lane & 15;
    const int bid = blockIdx.x;
    const int b = bid & 7;
    const int nmt = bid >> 3;            // 0..63
    const int n0 = (nmt >> 3) << 7;      // n128 base
    const int m0 = (nmt & 7) << 7;       // m128 base

    const int r8 = lane >> 3;                 // 0..7, == row&7
    const int gu = (lane & 7) ^ r8;           // pre-swizzled global unit
    const int qo0 = (n0 + wv * 8 + r8) * 64 + gu * 8;   // shorts
    const int qo1 = qo0 + 64 * 64;                      // +64 rows
    const int ko0 = (m0 + wv * 8 + r8) * 64 + gu * 8;
    const int ko1 = ko0 + 64 * 64;
    const int lc0 = wv * 512;                 // wave LDS chunk, it=0 (shorts)
    const int lc1 = 4096 + wv * 512;          // it=1

    f32x4 den[4][2];
#pragma unroll
    for (int i = 0; i < 4; i++)
#pragma unroll
        for (int j = 0; j < 2; j++) den[i][j] = (f32x4){0.f, 0.f, 0.f, 0.f};
    const f32x4 z = (f32x4){0.f, 0.f, 0.f, 0.f};

    {
        const short* qh = qb + ((size_t)(b * HH) << 16);
        const short* kh = kb + ((size_t)(b * HH) << 16);
        GLL16(qh + qo0, &Qs[0][lc0]);
        GLL16(qh + qo1, &Qs[0][lc1]);
        GLL16(kh + ko0, &Ks[0][lc0]);
        GLL16(kh + ko1, &Ks[0][lc1]);
    }

    for (int h = 0; h < HH; h++) {
        asm volatile("s_waitcnt vmcnt(0)" ::: "memory");  // this head's DMA landed
        __syncthreads();                                  // all waves see it
        if (h < HH - 1) {
            const int pn = (h + 1) & 1;
            const short* qh = qb + ((size_t)(b * HH + h + 1) << 16);
            const short* kh = kb + ((size_t)(b * HH + h + 1) << 16);
            GLL16(qh + qo0, &Qs[pn][lc0]);
            GLL16(qh + qo1, &Qs[pn][lc1]);
            GLL16(kh + ko0, &Ks[pn][lc0]);
            GLL16(kh + ko1, &Ks[pn][lc1]);
        }
        const int pb = h & 1;
        const int sw0 = (quad ^ (l16 & 7)) * 8;

        bf16x8 aq[4][2], bk[2][2];
#pragma unroll
        for (int t = 0; t < 4; t++) {
            const int row = wrow * 64 + t * 16 + l16;
            aq[t][0] = *reinterpret_cast<bf16x8*>(&Qs[pb][row * 64 + sw0]);
            aq[t][1] = *reinterpret_cast<bf16x8*>(&Qs[pb][row * 64 + (sw0 ^ 32)]);
        }
#pragma unroll
        for (int t = 0; t < 2; t++) {
            const int row = wcol * 32 + t * 16 + l16;
            bk[t][0] = *reinterpret_cast<bf16x8*>(&Ks[pb][row * 64 + sw0]);
            bk[t][1] = *reinterpret_cast<bf16x8*>(&Ks[pb][row * 64 + (sw0 ^ 32)]);
        }
#pragma unroll
        for (int nt = 0; nt < 4; nt++)
#pragma unroll
            for (int mt = 0; mt < 2; mt++) {
                f32x4 s = MFMA16(aq[nt][0], bk[mt][0], z);
                s = MFMA16(aq[nt][1], bk[mt][1], s);
#pragma unroll
                for (int r = 0; r < 4; r++)
                    den[nt][mt][r] += __builtin_amdgcn_exp2f(s[r] * SCL2E);
            }
    }

#pragma unroll
    for (int nt = 0; nt < 4; nt++)
#pragma unroll
        for (int mt = 0; mt < 2; mt++) {
            const int ntg = (n0 >> 4) + wrow * 4 + nt;
            const int mtg = (m0 >> 4) + wcol * 2 + mt;
            ushort4 o;
            o.x = (unsigned short)f2bf(1.0f / den[nt][mt][0]);
            o.y = (unsigned short)f2bf(1.0f / den[nt][mt][1]);
            o.z = (unsigned short)f2bf(1.0f / den[nt][mt][2]);
            o.w = (unsigned short)f2bf(1.0f / den[nt][mt][3]);
            *reinterpret_cast<ushort4*>(&invp[(((b * 64 + ntg) * 64 + mtg) * 64 + lane) * 4]) = o;
        }
}

// ---------- attention pass 2 v2 (proven ~53us) ----------
__global__ __launch_bounds__(256, 4)
void attn_pv2(const short* __restrict__ qb, const short* __restrict__ kb,
              const short* __restrict__ vtb, const short* __restrict__ invp,
              short* __restrict__ attn_out) {
    __shared__ __align__(16) short Ks[2][32 * 72];   // [m][d]
    __shared__ __align__(16) short Vs[2][64 * 40];   // [d][m]
    __shared__ __align__(16) short Ps[4][32 * 40];   // per-wave [n][m]

    const int tid = threadIdx.x, lane = tid & 63, wv = tid >> 6;
    const int quad = lane >> 4, l16 = lane & 15;
    const int bid = blockIdx.x;
    const int b = bid & 7;
    const int r = bid >> 3;              // 0..95
    const int n4 = r / 12;               // 0..7 (n128 tile)
    const int h = r - n4 * 12;
    const int nb = n4 << 7;
    const int bh = b * HH + h;

    bf16x8 aq[2][2];
#pragma unroll
    for (int nt = 0; nt < 2; nt++) {
        const short* qp = qb + (bh << 16) + ((nb + wv * 32 + nt * 16 + l16) << 6) + quad * 8;
        aq[nt][0] = *reinterpret_cast<const bf16x8*>(qp);
        aq[nt][1] = *reinterpret_cast<const bf16x8*>(qp + 32);
    }

    const f32x4 z = (f32x4){0.f, 0.f, 0.f, 0.f};
    f32x4 O[2][4];
#pragma unroll
    for (int nt = 0; nt < 2; nt++)
#pragma unroll
        for (int d = 0; d < 4; d++) O[nt][d] = z;

    const int krow = tid >> 3, koff = (tid & 7) * 8;   // K: 32 rows x 128B
    const int vrow = tid >> 2, voff = (tid & 3) * 8;   // V: 64 rows x 64B

    uint4 kreg = *reinterpret_cast<const uint4*>(kb + (bh << 16) + (krow << 6) + koff);
    uint4 vreg = *reinterpret_cast<const uint4*>(vtb + (bh << 16) + (vrow << 10) + voff);

    for (int it = 0; it < 32; it++) {
        const int p = it & 1;
        *reinterpret_cast<uint4*>(&Ks[p][krow * 72 + koff]) = kreg;
        *reinterpret_cast<uint4*>(&Vs[p][vrow * 40 + voff]) = vreg;
        __syncthreads();
        if (it < 31) {
            const int m1 = (it + 1) << 5;
            kreg = *reinterpret_cast<const uint4*>(kb + (bh << 16) + ((m1 + krow) << 6) + koff);
            vreg = *reinterpret_cast<const uint4*>(vtb + (bh << 16) + (vrow << 10) + m1 + voff);
        }
        const int m0 = it << 5;

#pragma unroll
        for (int mh = 0; mh < 2; mh++) {
            const bf16x8 k0 = *reinterpret_cast<bf16x8*>(&Ks[p][(mh * 16 + l16) * 72 + quad * 8]);
            const bf16x8 k1 = *reinterpret_cast<bf16x8*>(&Ks[p][(mh * 16 + l16) * 72 + quad * 8 + 32]);
            const int mt = (m0 >> 4) + mh;
#pragma unroll
            for (int nt = 0; nt < 2; nt++) {
                f32x4 s = MFMA16(aq[nt][0], k0, z);
                s = MFMA16(aq[nt][1], k1, s);
                const int ntg = (nb >> 4) + wv * 2 + nt;
                const ushort4 iv = *reinterpret_cast<const ushort4*>(
                    &invp[(((b * 64 + ntg) * 64 + mt) * 64 + lane) * 4]);
                Ps[wv][(nt * 16 + quad * 4 + 0) * 40 + mh * 16 + l16] = f2bf(__expf(s[0] * SCALE) * bf2f(iv.x));
                Ps[wv][(nt * 16 + quad * 4 + 1) * 40 + mh * 16 + l16] = f2bf(__expf(s[1] * SCALE) * bf2f(iv.y));
                Ps[wv][(nt * 16 + quad * 4 + 2) * 40 + mh * 16 + l16] = f2bf(__expf(s[2] * SCALE) * bf2f(iv.z));
                Ps[wv][(nt * 16 + quad * 4 + 3) * 40 + mh * 16 + l16] = f2bf(__expf(s[3] * SCALE) * bf2f(iv.w));
            }
        }
        __threadfence_block();  // intra-wave cross-lane RAW on Ps

        bf16x8 pa[2];
#pragma unroll
        for (int nt = 0; nt < 2; nt++)
            pa[nt] = *reinterpret_cast<bf16x8*>(&Ps[wv][(nt * 16 + l16) * 40 + quad * 8]);
#pragma unroll
        for (int dch = 0; dch < 4; dch++) {
            const bf16x8 vf = *reinterpret_cast<bf16x8*>(&Vs[p][(dch * 16 + l16) * 40 + quad * 8]);
#pragma unroll
            for (int nt = 0; nt < 2; nt++)
                O[nt][dch] = MFMA16(pa[nt], vf, O[nt][dch]);
        }
    }

#pragma unroll
    for (int nt = 0; nt < 2; nt++)
#pragma unroll
        for (int dch = 0; dch < 4; dch++) {
            const int col = h * 64 + dch * 16 + l16;
#pragma unroll
            for (int reg = 0; reg < 4; reg++) {
                const int n = nb + wv * 32 + nt * 16 + quad * 4 + reg;
                attn_out[(size_t)((b << 10) + n) * 768 + col] = f2bf(O[nt][dch][reg]);
            }
        }
}

// ---------- launch ----------
extern "C" void kernel_launch(void* const* d_in, const int* in_sizes, int n_in,
                              void* d_out, int out_size, void* d_ws, size_t ws_size,
                              hipStream_t stream) {
    const float* x     = (const float*)d_in[0];
    const float* w_qkv = (const float*)d_in[1];
    const float* w_out = (const float*)d_in[2];
    const float* b_out = (const float*)d_in[3];
    float* out = (float*)d_out;

    short* xb   = (short*)d_ws;                 // [8192][768]
    short* wT1  = xb  + 8192 * 768;             // [2304][768]
    short* wT2  = wT1 + 2304 * 768;             // [768][768]
    short* qb   = wT2 + 768 * 768;              // [b][h][n][d]
    short* kb   = qb  + 96 * 65536;
    short* vtb  = kb  + 96 * 65536;             // [b][h][d][n]
    short* attn = vtb + 96 * 65536;             // [8192][768]
    short* invp = attn + 8192 * 768;            // [b][nt][mt][lane][4]

    // fused prep: cast (6144) + w_qkv transpose (432) + w_out transpose (144)
    prep<<<6720, 256, 0, stream>>>(x, xb, w_qkv, wT1, w_out, wT2);

    gemm128<0><<<1152, 256, 0, stream>>>(
        xb, wT1, 768, qb, kb, vtb, nullptr, nullptr);

    attn_den5<<<512, 512, 0, stream>>>(qb, kb, invp);
    attn_pv2<<<768, 256, 0, stream>>>(qb, kb, vtb, invp, attn);

    gemm_o<<<768, 256, 0, stream>>>(attn, wT2, 768, out, b_out);
}